// Round 10
// baseline (46.803 us; speedup 1.0000x reference)
//
#include <hip/hip_runtime.h>

// Spatial transformer, bilinear sampling, NCHW fp32.
// X: (B, C, H, W) = (32, 3, 512, 512), theta: (B, 6), out: (B, C, H, W).
//
// R10: move gathers from the TA/vmem pipe to the DS pipe. Block = 64x16
//      output tile; exact source bbox from the 4 tile corners (identical
//      fma sequence as per-px math -> monotone -> provable bounds). ONE
//      channel staged at a time into a 32x88 LDS tile (11.3 KB -> 8
//      blocks/CU) with coalesced loads + ds_write_b64; border replication
//      baked in via clamped staging addresses. Per-px gathers become
//      2x ds_read2_b32 (DS pipe, parallel to TA). Per-px weights/offsets
//      precomputed once, reused for all 3 channels. Oversized bbox
//      (outlier theta, ~4% of images) -> block-uniform R8 fallback path.
//      Keeps: 4B-lane-stride mapping, nt stores, XCD-contiguous swizzle.

#define ST_H 512
#define ST_W 512
#define ST_C 3
#define ST_HW (ST_H * ST_W)
#define RMAX 32      // staged rows
#define PITCH 88     // staged floats per row (44 lanes x 2)
#define HALFP 44

typedef float f2 __attribute__((ext_vector_type(2)));
struct __attribute__((packed, aligned(4))) f2_a4 { f2 v; };

// The ONE coordinate formula (used for both corner-bbox and per-px eval;
// fma is weakly monotone in each operand -> tile extremes are at corners).
__device__ __forceinline__ void st_xy(float t00, float t01, float t02,
                                      float t10, float t11, float t12,
                                      int w, int h, float& x, float& y)
{
    const float STEP = (float)(2.0 / 511.0);
    const float xg  = fmaf((float)w, STEP, -1.0f);
    const float yg  = fmaf((float)h, STEP, -1.0f);
    const float xb0 = fmaf(t00, xg, t02);
    const float yb0 = fmaf(t10, xg, t12);
    x = (fmaf(t01, yg, xb0) + 1.0f) * 256.0f;
    y = (fmaf(t11, yg, yb0) + 1.0f) * 256.0f;
}

__global__ __launch_bounds__(256) void st_bilinear_kernel(
    const float* __restrict__ X,
    const float* __restrict__ theta,
    float* __restrict__ out,
    int chunk)
{
    __shared__ float sb[RMAX * PITCH];   // 11264 B

    // XCD swizzle: each XCD owns a contiguous range of blocks (grid % 8 == 0).
    int bid = blockIdx.x;
    bid = (bid & 7) * chunk + (bid >> 3);

    const int b   = bid >> 8;            // 256 tiles per image
    const int idx = bid & 255;
    const int tx  = idx & 7;             // 8 tiles of 64 px across
    const int ty  = idx >> 3;            // 32 tiles of 16 rows down
    const int w0t = tx << 6;
    const int h0t = ty << 4;

    const int tid  = (int)threadIdx.x;
    const int lane = tid & 63;
    const int wid  = tid >> 6;           // wave id 0..3
    const int w    = w0t + lane;

    const float* t = theta + b * 6;
    const float t00 = t[0], t01 = t[1], t02 = t[2];
    const float t10 = t[3], t11 = t[4], t12 = t[5];

    // ---- exact bbox from the 4 tile corners ----
    float xmin = 1e30f, xmax = -1e30f, ymin = 1e30f, ymax = -1e30f;
#pragma unroll
    for (int i = 0; i < 2; ++i)
#pragma unroll
        for (int j = 0; j < 2; ++j) {
            float xx, yy;
            st_xy(t00, t01, t02, t10, t11, t12,
                  w0t + i * 63, h0t + j * 15, xx, yy);
            xmin = fminf(xmin, xx); xmax = fmaxf(xmax, xx);
            ymin = fminf(ymin, yy); ymax = fmaxf(ymax, yy);
        }
    const int xlo = (int)floorf(xmin) - 1;
    const int ylo = (int)floorf(ymin) - 1;
    const int RX  = (int)floorf(xmax) + 2 - xlo + 1;
    const int RY  = (int)floorf(ymax) + 2 - ylo + 1;
    const bool fast = (RX <= PITCH) && (RY <= RMAX);   // block-uniform

    // ---- per-px precompute (4 px/thread: rows wid, wid+4, wid+8, wid+12) ----
    float wa[4], wb[4], wc[4], wd[4];
    int soff[4];                 // staged word offset (fast path)
    int ia[4], ib[4];            // global gather offsets (fallback)
    bool hi[4], lo[4];
    int opix[4];

#pragma unroll
    for (int k = 0; k < 4; ++k) {
        const int h = h0t + wid + (k << 2);
        float x, y;
        st_xy(t00, t01, t02, t10, t11, t12, w, h, x, y);

        const int x0 = (int)floorf(x);
        const int y0 = (int)floorf(y);

        const int x0c = min(max(x0, 0), ST_W - 1);
        const int x1c = min(max(x0 + 1, 0), ST_W - 1);
        const int y0c = min(max(y0, 0), ST_H - 1);
        const int y1c = min(max(y0 + 1, 0), ST_H - 1);

        // weights use CLIPPED coords cast to float (reference semantics)
        const float x0f = (float)x0c, x1f = (float)x1c;
        const float y0f = (float)y0c, y1f = (float)y1c;
        wa[k] = (x1f - x) * (y1f - y);
        wb[k] = (x1f - x) * (y - y0f);
        wc[k] = (x - x0f) * (y1f - y);
        wd[k] = (x - x0f) * (y - y0f);

        soff[k] = (y0 - ylo) * PITCH + (x0 - xlo);   // staged data pre-clamped

        const int xa = min(max(x0, 0), ST_W - 2);
        hi[k] = (x0 >= ST_W - 1);
        lo[k] = (x0 < 0);
        ia[k] = y0c * ST_W + xa;
        ib[k] = y1c * ST_W + xa;

        opix[k] = h * ST_W + w;
    }

    const float* __restrict__ Xb = X + (size_t)b * (ST_C * ST_HW);
    float* __restrict__ ob = out + (size_t)b * (ST_C * ST_HW);

    if (fast) {
#pragma unroll
        for (int c = 0; c < ST_C; ++c) {
            const float* __restrict__ Xc = Xb + c * ST_HW;
            if (c) __syncthreads();     // protect prior reads before restage
            // ---- stage channel c: rows wid+4*it, 44 lanes x 2 cols ----
#pragma unroll
            for (int it = 0; it < RMAX / 4; ++it) {
                const int row = wid + (it << 2);
                if (row < RY) {
                    const int grow = min(max(ylo + row, 0), ST_H - 1);
                    const float* __restrict__ rp = Xc + (grow << 9);
                    if (lane < HALFP) {
                        const int c0 = min(max(xlo + 2 * lane,     0), ST_W - 1);
                        const int c1 = min(max(xlo + 2 * lane + 1, 0), ST_W - 1);
                        f2 v; v.x = rp[c0]; v.y = rp[c1];
                        *(f2*)&sb[row * PITCH + 2 * lane] = v;   // ds_write_b64
                    }
                }
            }
            __syncthreads();
            // ---- gather from LDS (2x ds_read2_b32 per px) ----
#pragma unroll
            for (int k = 0; k < 4; ++k) {
                const float* sp = &sb[soff[k]];
                const float Ia = sp[0];
                const float Ic = sp[1];
                const float Ib = sp[PITCH];
                const float Id = sp[PITCH + 1];
                const float v = wa[k] * Ia + wb[k] * Ib + wc[k] * Ic + wd[k] * Id;
                // nontemporal: output has zero reuse
                __builtin_nontemporal_store(v, ob + c * ST_HW + opix[k]);
            }
        }
    } else {
        // ---- fallback: proven R8 per-px dwordx2 vmem gathers ----
#pragma unroll
        for (int k = 0; k < 4; ++k) {
#pragma unroll
            for (int c = 0; c < ST_C; ++c) {
                const float* __restrict__ Xc = Xb + c * ST_HW;
                const f2 p = ((const f2_a4*)(Xc + ia[k]))->v;   // (Ia, Ic)
                const f2 q = ((const f2_a4*)(Xc + ib[k]))->v;   // (Ib, Id)
                const float Ia = hi[k] ? p.y : p.x;
                const float Ic = lo[k] ? p.x : p.y;
                const float Ib = hi[k] ? q.y : q.x;
                const float Id = lo[k] ? q.x : q.y;
                const float v = wa[k] * Ia + wb[k] * Ib + wc[k] * Ic + wd[k] * Id;
                __builtin_nontemporal_store(v, ob + c * ST_HW + opix[k]);
            }
        }
    }
}

extern "C" void kernel_launch(void* const* d_in, const int* in_sizes, int n_in,
                              void* d_out, int out_size, void* d_ws, size_t ws_size,
                              hipStream_t stream) {
    const float* X     = (const float*)d_in[0];
    const float* theta = (const float*)d_in[1];
    float* out         = (float*)d_out;

    const int B = in_sizes[1] / 6;          // 32
    const int block = 256;                  // 64x16 px tile, 4 px/thread
    const int grid = B * 256;               // 8192 blocks, divisible by 8
    const int chunk = grid / 8;             // blocks per XCD

    st_bilinear_kernel<<<grid, block, 0, stream>>>(X, theta, out, chunk);
}